// Round 7
// baseline (447.127 us; speedup 1.0000x reference)
//
#include <hip/hip_runtime.h>
#include <math.h>

#define NN 8192
#define IN_DIM 64
#define GAT_EPS 1e-10f
#define ECAP 256           // per-row edge capacity; Binom(8192,0.005): mean 41, max ~75.
#define NV4 (NN * NN / 4)  // 16,777,216 fvec4 elements
#define NTHREADS 524288    // 2048 blocks x 256 — all resident (2048 thr/CU)
#define ROUNDS 8           // NV4 / NTHREADS / 4

typedef float fvec4 __attribute__((ext_vector_type(4)));

__device__ __forceinline__ unsigned nz4(fvec4 v) {
    return (unsigned)(v.x != 0.f) | ((unsigned)(v.y != 0.f) << 1) |
           ((unsigned)(v.z != 0.f) << 2) | ((unsigned)(v.w != 0.f) << 3);
}

// ---------------------------------------------------------------------------
// Kernel 0: zero per-row edge counters (ws is poisoned 0xAA each call).
// ---------------------------------------------------------------------------
__global__ void zero_cnt_kernel(int* __restrict__ cnt) {
    cnt[blockIdx.x * blockDim.x + threadIdx.x] = 0;
}

// ---------------------------------------------------------------------------
// Kernel 1: interleaved feature transform.
//   ftI[n*64 + c] = { feat[n].W_lin[c] + b_lin[c],  feat[n].W_lin[64+c] + b_lin[64+c] }
// ---------------------------------------------------------------------------
__global__ void ft_kernel(const float* __restrict__ features,
                          const float* __restrict__ W_lin,
                          const float* __restrict__ b_lin,
                          float2* __restrict__ ftI) {
    int gid = blockIdx.x * blockDim.x + threadIdx.x;   // n*64 + c
    int n = gid >> 6;
    int c = gid & 63;
    const float4* f4 = (const float4*)(features + (size_t)n * IN_DIM);
    const float4* w0 = (const float4*)(W_lin + (size_t)c * IN_DIM);
    const float4* w1 = (const float4*)(W_lin + (size_t)(64 + c) * IN_DIM);
    float a0 = 0.f, a1 = 0.f;
#pragma unroll
    for (int d = 0; d < IN_DIM / 4; ++d) {
        float4 f = f4[d];
        float4 u = w0[d];
        float4 v = w1[d];
        a0 += f.x * u.x + f.y * u.y + f.z * u.z + f.w * u.w;
        a1 += f.x * v.x + f.y * v.y + f.z * v.z + f.w * v.w;
    }
    ftI[gid] = make_float2(a0 + b_lin[c], a1 + b_lin[64 + c]);
}

// ---------------------------------------------------------------------------
// Kernel 2: column score factors. pdv[m] = { exp(f[m].Wa0_dst), exp(f[m].Wa1_dst) }
// Row factor exp(s_src+b) cancels in the softmax (rank-1 scores).
// ---------------------------------------------------------------------------
__global__ void score_kernel(const float* __restrict__ features,
                             const float* __restrict__ W_attn,
                             float2* __restrict__ pdv) {
    int n = blockIdx.x * blockDim.x + threadIdx.x;
    const float4* f4   = (const float4*)(features + (size_t)n * IN_DIM);
    const float4* wa0d = (const float4*)(W_attn + IN_DIM);
    const float4* wa1d = (const float4*)(W_attn + 3 * IN_DIM);
    float s0 = 0.f, s1 = 0.f;
#pragma unroll
    for (int d = 0; d < IN_DIM / 4; ++d) {
        float4 f = f4[d];
        float4 b = wa0d[d];
        float4 e = wa1d[d];
        s0 += f.x * b.x + f.y * b.y + f.z * b.z + f.w * b.w;
        s1 += f.x * e.x + f.y * e.y + f.z * e.z + f.w * e.w;
    }
    pdv[n] = make_float2(__expf(s0), __expf(s1));
}

// ---------------------------------------------------------------------------
// Kernel 3a: SCAN — fill-order grid-stride. All 524,288 threads resident;
// per round each thread pipelines 4 strided nontemporal 16B loads whose
// per-instruction addressing is lane-consecutive, so the chip sweeps
// contiguous windows exactly like the 6.6 TB/s fill kernels.
// Nonzero columns append to per-row global edge lists via atomicAdd
// (order irrelevant; adjacency is binary so only indices are stored).
// ---------------------------------------------------------------------------
__global__ void __launch_bounds__(256) scan_kernel(const float* __restrict__ adj,
                                                   int* __restrict__ cnt,
                                                   int* __restrict__ elist) {
    int tid = blockIdx.x * blockDim.x + threadIdx.x;   // 0..524287
    const fvec4* a4 = (const fvec4*)adj;

    auto process = [&](fvec4 v, int g) {
        unsigned m = nz4(v);
        if (m) {
            int row  = g >> 11;          // 2048 fvec4 per row
            int base = (g & 2047) * 4;
            int c = __popc(m);
            int pos = atomicAdd(&cnt[row], c);
            int* dst = elist + (size_t)row * ECAP;
            while (m) {
                int b = __ffs(m) - 1;
                m &= m - 1;
                if (pos < ECAP) dst[pos] = base + b;
                ++pos;
            }
        }
    };

    // prologue
    fvec4 v0 = __builtin_nontemporal_load(a4 + tid);
    fvec4 v1 = __builtin_nontemporal_load(a4 + tid + NTHREADS);
    fvec4 v2 = __builtin_nontemporal_load(a4 + tid + 2 * NTHREADS);
    fvec4 v3 = __builtin_nontemporal_load(a4 + tid + 3 * NTHREADS);

#pragma unroll
    for (int r = 0; r < ROUNDS; ++r) {
        fvec4 n0, n1, n2, n3;
        if (r < ROUNDS - 1) {
            int gn = tid + (4 * r + 4) * NTHREADS;
            n0 = __builtin_nontemporal_load(a4 + gn);
            n1 = __builtin_nontemporal_load(a4 + gn + NTHREADS);
            n2 = __builtin_nontemporal_load(a4 + gn + 2 * NTHREADS);
            n3 = __builtin_nontemporal_load(a4 + gn + 3 * NTHREADS);
        }
        int g = tid + 4 * r * NTHREADS;
        process(v0, g);
        process(v1, g + NTHREADS);
        process(v2, g + 2 * NTHREADS);
        process(v3, g + 3 * NTHREADS);
        v0 = n0; v1 = n1; v2 = n2; v3 = n3;
    }
}

// ---------------------------------------------------------------------------
// Kernel 3b: AGGREGATE — one wave per row. Edge list staged to LDS, batched
// gathers of pdv/ftI (L2-resident), normalize, ELU.
// ---------------------------------------------------------------------------
__global__ void __launch_bounds__(256) agg_kernel(const int* __restrict__ cnt,
                                                  const int* __restrict__ elist,
                                                  const float2* __restrict__ ftI,
                                                  const float2* __restrict__ pdv,
                                                  float* __restrict__ out) {
    __shared__ int ebuf[4][ECAP];
    int widx = threadIdx.x >> 6;
    int lane = threadIdx.x & 63;
    int n = blockIdx.x * 4 + widx;

    int count = cnt[n];
    if (count > ECAP) count = ECAP;   // defensive
    const int* src = elist + (size_t)n * ECAP;
    for (int e = lane; e < count; e += 64) ebuf[widx][e] = src[e];

    // self-loop (+I): weight pdv[n], value 1.0
    float2 ps = pdv[n];
    float2 fs = ftI[(size_t)n * 64 + lane];
    float acc0 = ps.x * fs.x, acc1 = ps.y * fs.y;
    float den0 = ps.x, den1 = ps.y;

    __syncthreads();

    const int* eb = ebuf[widx];
    int e = 0;
    for (; e + 8 <= count; e += 8) {
        int4 ma  = *(const int4*)&eb[e];
        int4 mbq = *(const int4*)&eb[e + 4];
        float2 p0 = pdv[ma.x],  p1 = pdv[ma.y],  p2 = pdv[ma.z],  p3 = pdv[ma.w];
        float2 p4 = pdv[mbq.x], p5 = pdv[mbq.y], p6 = pdv[mbq.z], p7 = pdv[mbq.w];
        float2 f0 = ftI[(size_t)ma.x * 64 + lane];
        float2 f1 = ftI[(size_t)ma.y * 64 + lane];
        float2 f2 = ftI[(size_t)ma.z * 64 + lane];
        float2 f3 = ftI[(size_t)ma.w * 64 + lane];
        float2 f4 = ftI[(size_t)mbq.x * 64 + lane];
        float2 f5 = ftI[(size_t)mbq.y * 64 + lane];
        float2 f6 = ftI[(size_t)mbq.z * 64 + lane];
        float2 f7 = ftI[(size_t)mbq.w * 64 + lane];
        acc0 += p0.x * f0.x + p1.x * f1.x + p2.x * f2.x + p3.x * f3.x
              + p4.x * f4.x + p5.x * f5.x + p6.x * f6.x + p7.x * f7.x;
        acc1 += p0.y * f0.y + p1.y * f1.y + p2.y * f2.y + p3.y * f3.y
              + p4.y * f4.y + p5.y * f5.y + p6.y * f6.y + p7.y * f7.y;
        den0 += p0.x + p1.x + p2.x + p3.x + p4.x + p5.x + p6.x + p7.x;
        den1 += p0.y + p1.y + p2.y + p3.y + p4.y + p5.y + p6.y + p7.y;
    }
    for (; e < count; ++e) {
        int m = eb[e];
        float2 p = pdv[m];
        float2 f = ftI[(size_t)m * 64 + lane];
        acc0 += p.x * f.x;
        acc1 += p.y * f.y;
        den0 += p.x;
        den1 += p.y;
    }

    float o0 = acc0 / (den0 + GAT_EPS);
    float o1 = acc1 / (den1 + GAT_EPS);
    o0 = o0 > 0.f ? o0 : expm1f(o0);
    o1 = o1 > 0.f ? o1 : expm1f(o1);
    out[(size_t)n * 128 + lane]      = o0;
    out[(size_t)n * 128 + 64 + lane] = o1;
}

extern "C" void kernel_launch(void* const* d_in, const int* in_sizes, int n_in,
                              void* d_out, int out_size, void* d_ws, size_t ws_size,
                              hipStream_t stream) {
    const float* adj      = (const float*)d_in[0];  // [N, N] binary
    const float* features = (const float*)d_in[1];  // [N, 64]
    const float* W_attn   = (const float*)d_in[2];  // [2, 128]
    // d_in[3] = b_attn: cancels in softmax normalization, unused
    const float* W_lin    = (const float*)d_in[4];  // [128, 64]
    const float* b_lin    = (const float*)d_in[5];  // [128]
    float* out = (float*)d_out;                     // [N, 128]

    float* ws = (float*)d_ws;
    float2* ftI  = (float2*)ws;                               // 4 MB
    float2* pdv  = (float2*)(ws + (size_t)NN * 128);          // 64 KB
    int*    cnt  = (int*)(ws + (size_t)NN * 128 + 2 * NN);    // 32 KB
    int*    elst = cnt + NN;                                  // 8 MB

    zero_cnt_kernel<<<NN / 256, 256, 0, stream>>>(cnt);
    ft_kernel<<<(NN * 64) / 256, 256, 0, stream>>>(features, W_lin, b_lin, ftI);
    score_kernel<<<NN / 256, 256, 0, stream>>>(features, W_attn, pdv);
    scan_kernel<<<NTHREADS / 256, 256, 0, stream>>>(adj, cnt, elst);
    agg_kernel<<<NN / 4, 256, 0, stream>>>(cnt, elst, ftI, pdv, out);
}

// Round 8
// 391.741 us; speedup vs baseline: 1.1414x; 1.1414x over previous
//
#include <hip/hip_runtime.h>
#include <math.h>

#define NN 8192
#define IN_DIM 64
#define GAT_EPS 1e-10f
#define ECAP 256   // per-row edge capacity; Binom(8192,0.005): mean 41, max ~80. 256 = safe.

typedef float fvec4 __attribute__((ext_vector_type(4)));

__device__ __forceinline__ unsigned nz4(fvec4 v) {
    return (unsigned)(v.x != 0.f) | ((unsigned)(v.y != 0.f) << 1) |
           ((unsigned)(v.z != 0.f) << 2) | ((unsigned)(v.w != 0.f) << 3);
}

// ---------------------------------------------------------------------------
// Kernel 1 (fused setup): blocks [0,2048) do the feature transform,
// blocks [2048,2080) do the score factors. One launch instead of two.
//   ftI[n*64 + c] = { feat[n].W_lin[c] + b_lin[c], feat[n].W_lin[64+c] + b_lin[64+c] }
//   pdv[m]        = { exp(feat[m].Wa0_dst), exp(feat[m].Wa1_dst) }
// Row factor exp(s_src+b) cancels in the softmax (rank-1 scores) — never computed.
// ---------------------------------------------------------------------------
__global__ void setup_kernel(const float* __restrict__ features,
                             const float* __restrict__ W_lin,
                             const float* __restrict__ b_lin,
                             const float* __restrict__ W_attn,
                             float2* __restrict__ ftI,
                             float2* __restrict__ pdv) {
    if (blockIdx.x < 2048) {
        int gid = blockIdx.x * blockDim.x + threadIdx.x;   // n*64 + c
        int n = gid >> 6;
        int c = gid & 63;
        const float4* f4 = (const float4*)(features + (size_t)n * IN_DIM);
        const float4* w0 = (const float4*)(W_lin + (size_t)c * IN_DIM);
        const float4* w1 = (const float4*)(W_lin + (size_t)(64 + c) * IN_DIM);
        float a0 = 0.f, a1 = 0.f;
#pragma unroll
        for (int d = 0; d < IN_DIM / 4; ++d) {
            float4 f = f4[d];
            float4 u = w0[d];
            float4 v = w1[d];
            a0 += f.x * u.x + f.y * u.y + f.z * u.z + f.w * u.w;
            a1 += f.x * v.x + f.y * v.y + f.z * v.z + f.w * v.w;
        }
        ftI[gid] = make_float2(a0 + b_lin[c], a1 + b_lin[64 + c]);
    } else {
        int n = (blockIdx.x - 2048) * blockDim.x + threadIdx.x;  // 32 blocks x 256 = 8192
        const float4* f4   = (const float4*)(features + (size_t)n * IN_DIM);
        const float4* wa0d = (const float4*)(W_attn + IN_DIM);
        const float4* wa1d = (const float4*)(W_attn + 3 * IN_DIM);
        float s0 = 0.f, s1 = 0.f;
#pragma unroll
        for (int d = 0; d < IN_DIM / 4; ++d) {
            float4 f = f4[d];
            float4 b = wa0d[d];
            float4 e = wa1d[d];
            s0 += f.x * b.x + f.y * b.y + f.z * b.z + f.w * b.w;
            s1 += f.x * e.x + f.y * e.y + f.z * e.z + f.w * e.w;
        }
        pdv[n] = make_float2(__expf(s0), __expf(s1));
    }
}

// ---------------------------------------------------------------------------
// Kernel 2: one wave per row (R6 structure — session best), phase-A stream
// pipelined 3 rounds (12 loads) ahead. Row-order access keeps each wave in
// one 32 KB page window (R7 showed fill-order's 8 MB strides regress).
// Phase B: LDS edge list drained 8-at-a-time; weight per edge = pdv[m]
// (binary adjacency, row softmax factor cancelled). Divide + ELU epilogue.
// ---------------------------------------------------------------------------
__global__ void __launch_bounds__(256) gat_agg_kernel(
        const float* __restrict__ adj,
        const float2* __restrict__ ftI,
        const float2* __restrict__ pdv,
        float* __restrict__ out) {
    __shared__ int edges[4][ECAP];
    __shared__ int ecnt[4];
    int widx = threadIdx.x >> 6;
    int lane = threadIdx.x & 63;
    int n = blockIdx.x * 4 + widx;
    int* ebuf = edges[widx];

    if (lane == 0) ecnt[widx] = 0;

    const fvec4* arow = (const fvec4*)(adj + (size_t)n * NN) + lane;

    // software pipeline: 3 rounds (12 loads, 12 KB/wave) in flight
    fvec4 q[3][4];
#pragma unroll
    for (int r = 0; r < 3; ++r) {
        const fvec4* p = arow + r * 256;
        q[r][0] = __builtin_nontemporal_load(p);
        q[r][1] = __builtin_nontemporal_load(p + 64);
        q[r][2] = __builtin_nontemporal_load(p + 128);
        q[r][3] = __builtin_nontemporal_load(p + 192);
    }

#pragma unroll
    for (int it = 0; it < 8; ++it) {   // fully unrolled; 1024 cols per round
        int slot = it % 3;
        fvec4 a0 = q[slot][0], a1 = q[slot][1], a2 = q[slot][2], a3 = q[slot][3];
        if (it < 5) {
            const fvec4* p = arow + (it + 3) * 256;
            q[slot][0] = __builtin_nontemporal_load(p);
            q[slot][1] = __builtin_nontemporal_load(p + 64);
            q[slot][2] = __builtin_nontemporal_load(p + 128);
            q[slot][3] = __builtin_nontemporal_load(p + 192);
        }
        unsigned mb = nz4(a0) | (nz4(a1) << 4) | (nz4(a2) << 8) | (nz4(a3) << 12);
        if (mb) {
            int c = __popc(mb);
            int pos = atomicAdd(&ecnt[widx], c);
            int megabase = it * 1024 + lane * 4;
            while (mb) {
                int b = __ffs(mb) - 1;
                mb &= mb - 1;
                ebuf[pos++] = megabase + ((b >> 2) << 8) + (b & 3);
            }
        }
    }

    // self-loop (+I): weight pdv[n], value 1.0
    float2 ps = pdv[n];
    float2 fs = ftI[(size_t)n * 64 + lane];
    float acc0 = ps.x * fs.x, acc1 = ps.y * fs.y;
    float den0 = ps.x, den1 = ps.y;

    __syncthreads();

    int count = ecnt[widx];
    int e = 0;
    for (; e + 8 <= count; e += 8) {
        int4 ma  = *(const int4*)&ebuf[e];
        int4 mbq = *(const int4*)&ebuf[e + 4];
        float2 p0 = pdv[ma.x],  p1 = pdv[ma.y],  p2 = pdv[ma.z],  p3 = pdv[ma.w];
        float2 p4 = pdv[mbq.x], p5 = pdv[mbq.y], p6 = pdv[mbq.z], p7 = pdv[mbq.w];
        float2 f0 = ftI[(size_t)ma.x * 64 + lane];
        float2 f1 = ftI[(size_t)ma.y * 64 + lane];
        float2 f2 = ftI[(size_t)ma.z * 64 + lane];
        float2 f3 = ftI[(size_t)ma.w * 64 + lane];
        float2 f4 = ftI[(size_t)mbq.x * 64 + lane];
        float2 f5 = ftI[(size_t)mbq.y * 64 + lane];
        float2 f6 = ftI[(size_t)mbq.z * 64 + lane];
        float2 f7 = ftI[(size_t)mbq.w * 64 + lane];
        acc0 += p0.x * f0.x + p1.x * f1.x + p2.x * f2.x + p3.x * f3.x
              + p4.x * f4.x + p5.x * f5.x + p6.x * f6.x + p7.x * f7.x;
        acc1 += p0.y * f0.y + p1.y * f1.y + p2.y * f2.y + p3.y * f3.y
              + p4.y * f4.y + p5.y * f5.y + p6.y * f6.y + p7.y * f7.y;
        den0 += p0.x + p1.x + p2.x + p3.x + p4.x + p5.x + p6.x + p7.x;
        den1 += p0.y + p1.y + p2.y + p3.y + p4.y + p5.y + p6.y + p7.y;
    }
    for (; e < count; ++e) {
        int m = ebuf[e];
        float2 p = pdv[m];
        float2 f = ftI[(size_t)m * 64 + lane];
        acc0 += p.x * f.x;
        acc1 += p.y * f.y;
        den0 += p.x;
        den1 += p.y;
    }

    float o0 = acc0 / (den0 + GAT_EPS);
    float o1 = acc1 / (den1 + GAT_EPS);
    o0 = o0 > 0.f ? o0 : expm1f(o0);
    o1 = o1 > 0.f ? o1 : expm1f(o1);
    out[(size_t)n * 128 + lane]      = o0;
    out[(size_t)n * 128 + 64 + lane] = o1;
}

extern "C" void kernel_launch(void* const* d_in, const int* in_sizes, int n_in,
                              void* d_out, int out_size, void* d_ws, size_t ws_size,
                              hipStream_t stream) {
    const float* adj      = (const float*)d_in[0];  // [N, N] binary
    const float* features = (const float*)d_in[1];  // [N, 64]
    const float* W_attn   = (const float*)d_in[2];  // [2, 128]
    // d_in[3] = b_attn: cancels in softmax normalization, unused
    const float* W_lin    = (const float*)d_in[4];  // [128, 64]
    const float* b_lin    = (const float*)d_in[5];  // [128]
    float* out = (float*)d_out;                     // [N, 128]

    float* ws = (float*)d_ws;
    float2* ftI = (float2*)ws;                       // 4 MB
    float2* pdv = (float2*)(ws + (size_t)NN * 128);  // 64 KB

    setup_kernel<<<2048 + 32, 256, 0, stream>>>(features, W_lin, b_lin, W_attn, ftI, pdv);
    gat_agg_kernel<<<NN / 4, 256, 0, stream>>>(adj, ftI, pdv, out);
}